// Round 2
// baseline (233.442 us; speedup 1.0000x reference)
//
#include <hip/hip_runtime.h>
#include <math.h>

#define T_TOTAL 262144
#define HIDN 20
#define IND 9
#define CHUNK 256
#define WARM 96
#define MAXST (WARM + CHUNK + 1)   // iterations per chunk (<= 353)
#define NBLK (T_TOTAL / CHUNK)     // 1024 blocks

__device__ __forceinline__ float sigf(float x) {
    return __builtin_amdgcn_rcpf(1.0f + __expf(-x));
}
__device__ __forceinline__ float tanhfst(float x) {
    return 1.0f - 2.0f * __builtin_amdgcn_rcpf(1.0f + __expf(2.0f * x));
}

// Chunked LSTM scan with warmup. Lanes 0-19: layer1 units; lanes 20-39:
// layer2 W_ih2 half (and state owner); lanes 40-59: layer2 W_hh2 half;
// lanes 60-63 idle (zero weights). Layer 2 runs one step behind layer 1.
__global__ __launch_bounds__(64, 1)
void lstm_scan(const float* __restrict__ x,
               const float* __restrict__ w_ih1, const float* __restrict__ w_hh1,
               const float* __restrict__ b1,
               const float* __restrict__ w_ih2, const float* __restrict__ w_hh2,
               const float* __restrict__ b2,
               const float* __restrict__ w_p, const float* __restrict__ b_p,
               float* __restrict__ out)
{
    __shared__ __align__(16) float xbuf[MAXST * 12];   // x padded to stride 12 for b128 reads
    __shared__ __align__(16) float hcur[64];           // h1 at [0..19], h2 at [32..51]
    __shared__ __align__(16) float h2out[CHUNK * HIDN];

    const int lane = threadIdx.x;
    const int blk  = blockIdx.x;
    const int t0   = blk * CHUNK;
    const int start = (t0 >= WARM) ? (t0 - WARM) : 0;
    const int endt  = t0 + CHUNK;        // loop runs s in [start, endt]
    const int nst   = endt - start + 1;

    // ---- stage x chunk into LDS (clamped at T-1 for the final padded step)
    for (int idx = lane; idx < nst * IND; idx += 64) {
        int stp = idx / IND, d = idx - stp * IND;
        int gt = start + stp; if (gt > T_TOTAL - 1) gt = T_TOTAL - 1;
        xbuf[stp * 12 + d] = x[gt * IND + d];
    }
    hcur[lane] = 0.0f;

    // ---- per-lane weight registers
    float wv[4][HIDN];   // dot-20 weights (Whh1 | Wih2 | Whh2 | zero)
    float wx[4][IND];    // x-projection weights (layer-1 lanes only)
    float bias[4];
    {
        const int grp = lane / 20;          // 0,1,2,3
        const int k   = lane - grp * 20;
        #pragma unroll
        for (int q = 0; q < 4; ++q) {
            const int row = q * HIDN + k;   // PyTorch gate order i,f,g,o
            #pragma unroll
            for (int j = 0; j < HIDN; ++j) {
                float w = 0.0f;
                if (grp == 0)      w = w_hh1[row * HIDN + j];
                else if (grp == 1) w = w_ih2[row * HIDN + j];
                else if (grp == 2) w = w_hh2[row * HIDN + j];
                wv[q][j] = w;
            }
            #pragma unroll
            for (int d = 0; d < IND; ++d)
                wx[q][d] = (grp == 0) ? w_ih1[row * IND + d] : 0.0f;
            bias[q] = (grp == 0) ? b1[row] : ((grp == 1) ? b2[row] : 0.0f);
        }
    }
    __syncthreads();

    const float* vbase = (lane < 40) ? hcur : (hcur + 32);
    float c = 0.0f, h = 0.0f;

    for (int s = start; s <= endt; ++s) {
        // broadcast reads: h1 (lanes<40) or h2 (lanes>=40); 5x ds_read_b128
        float v[HIDN];
        {
            const float4* vb4 = (const float4*)vbase;
            float4 q0 = vb4[0], q1 = vb4[1], q2 = vb4[2], q3 = vb4[3], q4 = vb4[4];
            v[0]=q0.x; v[1]=q0.y; v[2]=q0.z; v[3]=q0.w;
            v[4]=q1.x; v[5]=q1.y; v[6]=q1.z; v[7]=q1.w;
            v[8]=q2.x; v[9]=q2.y; v[10]=q2.z; v[11]=q2.w;
            v[12]=q3.x; v[13]=q3.y; v[14]=q3.z; v[15]=q3.w;
            v[16]=q4.x; v[17]=q4.y; v[18]=q4.z; v[19]=q4.w;
        }
        float xv[IND];
        {
            const float* xr = &xbuf[(s - start) * 12];
            float4 xa = *(const float4*)xr;
            float4 xb = *(const float4*)(xr + 4);
            xv[0]=xa.x; xv[1]=xa.y; xv[2]=xa.z; xv[3]=xa.w;
            xv[4]=xb.x; xv[5]=xb.y; xv[6]=xb.z; xv[7]=xb.w;
            xv[8]=xr[8];
        }

        float a[4];
        #pragma unroll
        for (int q = 0; q < 4; ++q) {
            float acc = bias[q];
            #pragma unroll
            for (int d = 0; d < IND; ++d) acc += wx[q][d] * xv[d];
            #pragma unroll
            for (int j = 0; j < HIDN; ++j) acc += wv[q][j] * v[j];
            a[q] = acc;
        }
        // combine layer-2 halves: lane 20+k += lane 40+k
        #pragma unroll
        for (int q = 0; q < 4; ++q) {
            float other = __shfl(a[q], lane + 20, 64);
            if (lane >= 20 && lane < 40) a[q] += other;
        }

        const float gi = sigf(a[0]);
        const float gf = sigf(a[1]);
        const float gg = tanhfst(a[2]);
        const float go = sigf(a[3]);
        const float cn = gf * c + gi * gg;
        const float hn = go * tanhfst(cn);
        // layer-2 lanes must not commit the fictitious step at s==start
        const bool commit = (lane < 20) || (s > start);
        c = commit ? cn : 0.0f;
        h = commit ? hn : 0.0f;

        if (lane < 20) {
            hcur[lane] = h;
        } else if (lane < 40) {
            hcur[32 + (lane - 20)] = h;
            const int tt = s - 1;              // h2[tt] just computed
            if (tt >= t0) h2out[(tt - t0) * HIDN + (lane - 20)] = h;
        }
        __syncthreads();   // single wave: waitcnt + cheap barrier
    }

    // ---- projection epilogue: out[t] = w_p . h2[t] + b_p
    float wp[HIDN];
    #pragma unroll
    for (int j = 0; j < HIDN; ++j) wp[j] = w_p[j];
    const float bp = b_p[0];
    for (int tt = lane; tt < CHUNK; tt += 64) {
        float acc = bp;
        #pragma unroll
        for (int j = 0; j < HIDN; ++j) acc += wp[j] * h2out[tt * HIDN + j];
        out[t0 + tt] = acc;
    }
}

extern "C" void kernel_launch(void* const* d_in, const int* in_sizes, int n_in,
                              void* d_out, int out_size, void* d_ws, size_t ws_size,
                              hipStream_t stream) {
    const float* x     = (const float*)d_in[0];
    const float* w_ih1 = (const float*)d_in[1];
    const float* w_hh1 = (const float*)d_in[2];
    const float* b1    = (const float*)d_in[3];
    const float* w_ih2 = (const float*)d_in[4];
    const float* w_hh2 = (const float*)d_in[5];
    const float* b2    = (const float*)d_in[6];
    const float* w_p   = (const float*)d_in[7];
    const float* b_p   = (const float*)d_in[8];
    float* out = (float*)d_out;

    lstm_scan<<<NBLK, 64, 0, stream>>>(x, w_ih1, w_hh1, b1,
                                       w_ih2, w_hh2, b2, w_p, b_p, out);
}